// Round 15
// baseline (386.422 us; speedup 1.0000x reference)
//
#include <hip/hip_runtime.h>

// Problem constants (fixed by the reference)
#define NN 200000   // nodes
#define CC 256      // channels
#define NG 512      // graphs/segments

typedef __attribute__((ext_vector_type(8))) __bf16 bf16x8;
typedef __attribute__((ext_vector_type(16))) float f32x16;

typedef unsigned short u16;

#define VWAITN(n) asm volatile("s_waitcnt vmcnt(%0)" :: "i"(n) : "memory")
#define LWAIT0()  asm volatile("s_waitcnt lgkmcnt(0)" ::: "memory")
#define SBAR() __builtin_amdgcn_s_barrier()

__device__ __forceinline__ u16 f2bf(float f) {
  union { float f; unsigned u; } v; v.f = f;
  unsigned u = v.u;
  u += 0x7fffu + ((u >> 16) & 1u);   // RNE
  return (u16)(u >> 16);
}
__device__ __forceinline__ unsigned pack2(float a, float b) {
  return (unsigned)f2bf(a) | ((unsigned)f2bf(b) << 16);
}
__device__ __forceinline__ float bflo(unsigned u){ union{unsigned u; float f;} x; x.u = u << 16; return x.f; }
__device__ __forceinline__ float bfhi(unsigned u){ union{unsigned u; float f;} x; x.u = u & 0xffff0000u; return x.f; }

// ---------------------------------------------------------------------------
// K0: prep weights into 32x32x16 MFMA A-operand fragment slices (16 KB each).
//  Slice order: 0..3 K-even, 4..7 Q-even, 8..11 K-odd, 12..15 Q-odd,
//  16..23 V, 24..31 Wo.  (unchanged — numerically proven)
// ---------------------------------------------------------------------------
__global__ __launch_bounds__(256) void prep_kernel(
    const float* __restrict__ Wq, const float* __restrict__ Wk,
    const float* __restrict__ Wv, const float* __restrict__ Wo,
    u16* __restrict__ Wall) {
  int idx = blockIdx.x * 256 + threadIdx.x;     // 0..262143
  int s = idx >> 13;
  int inner = idx & 8191;
  int ks = inner >> 9;
  int l = (inner >> 3) & 63;
  int j = inner & 7;
  int r = l & 31, hi5 = l >> 5;
  int k = ks * 16 + hi5 * 8 + j;
  const float* W; int c0;
  if (s < 16) {
    int p = s >> 3, r4 = s & 7;
    if (r4 < 4) { W = Wk; c0 = r4 * 64 + p * 32; }
    else        { W = Wq; c0 = (r4 - 4) * 64 + p * 32; }
  } else if (s < 24) { W = Wv; c0 = (s - 16) * 32; }
  else               { W = Wo; c0 = (s - 24) * 32; }
  Wall[idx] = f2bf(W[k * 256 + c0 + r]);
}

// ---------------------------------------------------------------------------
// K1: segment boundaries from sorted batch.
// ---------------------------------------------------------------------------
__global__ __launch_bounds__(256) void seg_bounds_kernel(
    const int* __restrict__ batch, int* __restrict__ seg_start, int n) {
  int i = blockIdx.x * 256 + threadIdx.x;
  if (i >= n) return;
  int a = batch[i];
  int b = (i + 1 < n) ? batch[i + 1] : NG;
  for (int g = a + 1; g <= b; ++g) seg_start[g] = i + 1;
  if (i == 0) for (int g = 0; g <= a; ++g) seg_start[g] = 0;
}

// ---------------------------------------------------------------------------
// Stage one 16 KB W slice into LDS: 4 waves x 4 reps x 64 lanes x 16 B.
// 4 global_load_lds per wave -> vmcnt +4 per staged slice per wave.
// ---------------------------------------------------------------------------
__device__ __forceinline__ void stage_slice(
    const u16* __restrict__ Wall, u16* dst_base, int s, int w, int lane) {
#pragma unroll
  for (int rep = 0; rep < 4; ++rep) {
    const u16* src = Wall + (size_t)s * 8192 + ((w * 4 + rep) * 64 + lane) * 8;
    u16* dst = dst_base + (w * 4 + rep) * 512;
    __builtin_amdgcn_global_load_lds(
        (const __attribute__((address_space(1))) void*)src,
        (__attribute__((address_space(3))) void*)dst, 16, 0, 0);
  }
}

// ---------------------------------------------------------------------------
// One 32(dims)x32(nodes) slice over K=256: A-frags from LDS (16 ds_read_b128),
// B (x) from registers.  SINGLE acc chain (R15: -16 regs for occupancy; dep
// latency hidden by the extra resident wave per SIMD).
// ---------------------------------------------------------------------------
__device__ __forceinline__ f32x16 gemm_lds(
    const u16* buf, const bf16x8 xfr[16], int lane) {
  f32x16 acc = {0.f,0.f,0.f,0.f,0.f,0.f,0.f,0.f,0.f,0.f,0.f,0.f,0.f,0.f,0.f,0.f};
#pragma unroll
  for (int ks = 0; ks < 16; ++ks) {
    bf16x8 f0 = *reinterpret_cast<const bf16x8*>(&buf[(ks * 64 + lane) * 8]);
    acc = __builtin_amdgcn_mfma_f32_32x32x16_bf16(f0, xfr[ks], acc, 0, 0, 0);
  }
  return acc;
}

// ---------------------------------------------------------------------------
// K2: fused QKV + scores.  4 waves x 32 nodes = 128 nodes/block.  R14 body,
//  launch_bounds(256,3): cap ~170 unified regs -> 3 waves/SIMD residency.
//  2 LDS buffers (depth-1), counted vmcnt + raw s_barrier, biases in LDS,
//  tail index-clamped -> vmcnt-uniform blocks.
// ---------------------------------------------------------------------------
__global__ __launch_bounds__(256, 3) void qkv_scores_kernel(
    const float* __restrict__ x, const u16* __restrict__ Wall,
    const float* __restrict__ bq, const float* __restrict__ bk,
    const float* __restrict__ bv,
    u16* __restrict__ v_out,              // [NN][256] bf16
    float* __restrict__ scores) {         // [NN][16]
  __shared__ u16 Wbuf[2][8192];
  __shared__ float biasL[768];            // [bk | bq | bv]

  const int t = threadIdx.x;
  const int w = t >> 6, lane = t & 63;
  const int col = lane & 31, hi5 = lane >> 5;
  int n = blockIdx.x * 128 + w * 32 + col;
  if (n >= NN) n = NN - 1;                // clamp: duplicates write same values

  // ---- B-frags: x^T, persistent (64 VGPR). frag kb: k = kb*16+hi5*8+j ----
  bf16x8 xfr[16];
#pragma unroll
  for (int kb = 0; kb < 16; ++kb) {
    const float* px = x + (size_t)n * CC + kb * 16 + hi5 * 8;
    float4 a0 = *reinterpret_cast<const float4*>(px);
    float4 a1 = *reinterpret_cast<const float4*>(px + 4);
    uint4 u = {pack2(a0.x, a0.y), pack2(a0.z, a0.w),
               pack2(a1.x, a1.y), pack2(a1.z, a1.w)};
    xfr[kb] = *reinterpret_cast<bf16x8*>(&u);
  }
  // biases -> LDS (one-time; consumed via ds_read, off the vm counter)
  biasL[t] = bk[t];
  biasL[256 + t] = bq[t];
  biasL[512 + t] = bv[t];

  stage_slice(Wall, Wbuf[0], 0, w, lane);
  LWAIT0();                               // bias LDS writes visible pre-barrier

  float sp[16];
#pragma unroll
  for (int i = 0; i < 16; ++i) sp[i] = 0.f;

  int bi = 0;                             // LDS buffer holding slice sl

  // ---- K/Q phases: slices 0..15, in-lane fold ----
#pragma unroll 1
  for (int p = 0; p < 2; ++p) {
    unsigned kph[4][8];          // k packed bf16, head g, this half
#pragma unroll
    for (int g = 0; g < 4; ++g) {
      VWAITN(0);                 // stage(sl) landed (only own stage in flight)
      SBAR();
      stage_slice(Wall, Wbuf[bi ^ 1], p * 8 + g + 1, w, lane);
      f32x16 acc = gemm_lds(Wbuf[bi], xfr, lane);
      bi ^= 1;
#pragma unroll
      for (int q = 0; q < 4; ++q) {
        float4 b4 = *reinterpret_cast<const float4*>(
            &biasL[g * 64 + p * 32 + q * 8 + hi5 * 4]);
        kph[g][q * 2]     = pack2(acc[4 * q] + b4.x, acc[4 * q + 1] + b4.y);
        kph[g][q * 2 + 1] = pack2(acc[4 * q + 2] + b4.z, acc[4 * q + 3] + b4.w);
      }
    }
#pragma unroll
    for (int h = 0; h < 4; ++h) {
      VWAITN(0);
      SBAR();
      stage_slice(Wall, Wbuf[bi ^ 1], p * 8 + 5 + h, w, lane);
      f32x16 acc = gemm_lds(Wbuf[bi], xfr, lane);
      bi ^= 1;
#pragma unroll
      for (int q = 0; q < 4; ++q) {
        float4 b4 = *reinterpret_cast<const float4*>(
            &biasL[256 + h * 64 + p * 32 + q * 8 + hi5 * 4]);
        float q0 = acc[4 * q] + b4.x, q1 = acc[4 * q + 1] + b4.y;
        float q2 = acc[4 * q + 2] + b4.z, q3 = acc[4 * q + 3] + b4.w;
#pragma unroll
        for (int g = 0; g < 4; ++g) {
          unsigned k01 = kph[g][q * 2];
          unsigned k23 = kph[g][q * 2 + 1];
          sp[h * 4 + g] += q0 * bflo(k01) + q1 * bfhi(k01) +
                           q2 * bflo(k23) + q3 * bfhi(k23);
        }
      }
    }
  }

  // ---- scores reduce + store (4 stores, newer than stage(16)) ----
#pragma unroll
  for (int i = 0; i < 16; ++i) sp[i] += __shfl_xor(sp[i], 32, 64);
  if (hi5 == 0) {
#pragma unroll
    for (int q = 0; q < 4; ++q) {
      float4 o = {sp[q * 4] * 0.125f, sp[q * 4 + 1] * 0.125f,
                  sp[q * 4 + 2] * 0.125f, sp[q * 4 + 3] * 0.125f};
      *reinterpret_cast<float4*>(scores + (size_t)n * 16 + q * 4) = o;
    }
  }

  // ---- V phase: slices 16..23.  FIFO: 4 stores newer than awaited stage ----
#pragma unroll
  for (int sv = 0; sv < 8; ++sv) {
    VWAITN(4);                  // retire stage(16+sv); 4 stores stay in flight
    SBAR();
    if (sv < 7) stage_slice(Wall, Wbuf[bi ^ 1], 17 + sv, w, lane);
    f32x16 acc = gemm_lds(Wbuf[bi], xfr, lane);
    bi ^= 1;
#pragma unroll
    for (int q = 0; q < 4; ++q) {
      int d0 = sv * 32 + q * 8 + hi5 * 4;
      float4 b4 = *reinterpret_cast<const float4*>(&biasL[512 + d0]);
      uint2 pk = {pack2(acc[4 * q] + b4.x, acc[4 * q + 1] + b4.y),
                  pack2(acc[4 * q + 2] + b4.z, acc[4 * q + 3] + b4.w)};
      *reinterpret_cast<uint2*>(v_out + (size_t)n * CC + d0) = pk;
    }
  }
}

// ---------------------------------------------------------------------------
// K3: per-segment max & exp-sum over the 16 score columns (block per segment).
// ---------------------------------------------------------------------------
__global__ __launch_bounds__(256) void seg_softmax_kernel(
    const float* __restrict__ scores, const int* __restrict__ seg_start,
    float* __restrict__ seg_max, float* __restrict__ seg_sum) {
  __shared__ float red[256];
  int g = blockIdx.x;
  int s = seg_start[g], e = seg_start[g + 1];
  int t = threadIdx.x;
  int col = t & 15, sub = t >> 4;

  float m = -INFINITY;
  for (int i = s + sub; i < e; i += 16)
    m = fmaxf(m, scores[(size_t)i * 16 + col]);
  red[t] = m;
  __syncthreads();
  for (int step = 8; step >= 1; step >>= 1) {
    if (sub < step) red[t] = fmaxf(red[t], red[t + step * 16]);
    __syncthreads();
  }
  if (t < 16) seg_max[g * 16 + t] = red[t];
  float mcol = red[col];
  __syncthreads();

  float sum = 0.f;
  for (int i = s + sub; i < e; i += 16)
    sum += expf(scores[(size_t)i * 16 + col] - mcol);
  red[t] = sum;
  __syncthreads();
  for (int step = 8; step >= 1; step >>= 1) {
    if (sub < step) red[t] += red[t + step * 16];
    __syncthreads();
  }
  if (t < 16) seg_sum[g * 16 + t] = red[t];
}

// ---------------------------------------------------------------------------
// K4: fused att + att.v + output GEMM (+bo) + att_mean.  2-buffer depth-1
//     pipeline; bo in LDS; clamped tail; launch_bounds(256,3).
// ---------------------------------------------------------------------------
__global__ __launch_bounds__(256, 3) void out_kernel(
    const u16* __restrict__ v_bf, const float* __restrict__ scores,
    const int* __restrict__ batch, const float* __restrict__ seg_max,
    const float* __restrict__ seg_sum, const u16* __restrict__ Wall,
    const float* __restrict__ bo, float* __restrict__ out,
    float* __restrict__ att_mean) {
  __shared__ u16 Wbuf[2][8192];
  __shared__ float boL[256];

  const int t = threadIdx.x;
  const int w = t >> 6, lane = t & 63;
  const int col = lane & 31, hi5 = lane >> 5;
  int n = blockIdx.x * 128 + w * 32 + col;
  if (n >= NN) n = NN - 1;                // clamp: duplicates write same values

  // ---- att[16] for this lane's node ----
  int b = batch[n];
  float att[16];
#pragma unroll
  for (int q = 0; q < 4; ++q) {
    float4 sc = *reinterpret_cast<const float4*>(scores + (size_t)n * 16 + q * 4);
    float4 mx = *reinterpret_cast<const float4*>(seg_max + b * 16 + q * 4);
    float4 sm = *reinterpret_cast<const float4*>(seg_sum + b * 16 + q * 4);
    att[q * 4 + 0] = expf(sc.x - mx.x) / (sm.x + 1e-16f);
    att[q * 4 + 1] = expf(sc.y - mx.y) / (sm.y + 1e-16f);
    att[q * 4 + 2] = expf(sc.z - mx.z) / (sm.z + 1e-16f);
    att[q * 4 + 3] = expf(sc.w - mx.w) / (sm.w + 1e-16f);
  }

  boL[t] = bo[t];

  // att_mean store (older than stage(24); retires with first VWAIT)
  if (hi5 == 0) {
    float4 am;
    am.x = 0.25f * (att[0] + att[4] + att[8] + att[12]);
    am.y = 0.25f * (att[1] + att[5] + att[9] + att[13]);
    am.z = 0.25f * (att[2] + att[6] + att[10] + att[14]);
    am.w = 0.25f * (att[3] + att[7] + att[11] + att[15]);
    *reinterpret_cast<float4*>(att_mean + (size_t)n * 4) = am;
  }

  stage_slice(Wall, Wbuf[0], 24, w, lane);

  // ---- oa^T B-frags: oa[n][h*64+dd] = sum_g att[h*4+g]*v[n][g*64+dd] ----
  // Processed per dw to keep vv transient (16 regs live, not 64).
  bf16x8 oaf[16];
#pragma unroll
  for (int dw = 0; dw < 4; ++dw) {
    float vr[4][8];
#pragma unroll
    for (int g = 0; g < 4; ++g) {
      uint4 u4 = *reinterpret_cast<const uint4*>(
          v_bf + (size_t)n * CC + g * 64 + dw * 16 + hi5 * 8);
      vr[g][0] = bflo(u4.x); vr[g][1] = bfhi(u4.x);
      vr[g][2] = bflo(u4.y); vr[g][3] = bfhi(u4.y);
      vr[g][4] = bflo(u4.z); vr[g][5] = bfhi(u4.z);
      vr[g][6] = bflo(u4.w); vr[g][7] = bfhi(u4.w);
    }
#pragma unroll
    for (int h = 0; h < 4; ++h) {
      unsigned res[4];
#pragma unroll
      for (int jj = 0; jj < 4; ++jj) {
        float lo = att[h * 4 + 0] * vr[0][2 * jj] + att[h * 4 + 1] * vr[1][2 * jj] +
                   att[h * 4 + 2] * vr[2][2 * jj] + att[h * 4 + 3] * vr[3][2 * jj];
        float hf = att[h * 4 + 0] * vr[0][2 * jj + 1] + att[h * 4 + 1] * vr[1][2 * jj + 1] +
                   att[h * 4 + 2] * vr[2][2 * jj + 1] + att[h * 4 + 3] * vr[3][2 * jj + 1];
        res[jj] = pack2(lo, hf);
      }
      uint4 u = {res[0], res[1], res[2], res[3]};
      oaf[h * 4 + dw] = *reinterpret_cast<bf16x8*>(&u);
    }
  }
  LWAIT0();                               // boL visible pre-barrier

  // ---- output GEMM: 8 Wo slices, depth-1 counted pipeline ----
  int bi = 0;
#pragma unroll
  for (int so = 0; so < 8; ++so) {
    if (so == 0) { VWAITN(0); }  // stage(24) landed (retires att_mean/v loads)
    else         { VWAITN(4); }  // retire stage(24+so); 4 out-stores in flight
    SBAR();
    if (so < 7) stage_slice(Wall, Wbuf[bi ^ 1], 25 + so, w, lane);
    f32x16 acc = gemm_lds(Wbuf[bi], oaf, lane);
    bi ^= 1;
#pragma unroll
    for (int q = 0; q < 4; ++q) {
      int c0 = so * 32 + q * 8 + hi5 * 4;
      float4 b4 = *reinterpret_cast<const float4*>(&boL[c0]);
      float4 o = {acc[4 * q] + b4.x, acc[4 * q + 1] + b4.y,
                  acc[4 * q + 2] + b4.z, acc[4 * q + 3] + b4.w};
      *reinterpret_cast<float4*>(out + (size_t)n * CC + c0) = o;
    }
  }
}

// ---------------------------------------------------------------------------
extern "C" void kernel_launch(void* const* d_in, const int* in_sizes, int n_in,
                              void* d_out, int out_size, void* d_ws, size_t ws_size,
                              hipStream_t stream) {
  const float* x  = (const float*)d_in[0];
  const int* batch = (const int*)d_in[1];
  const float* Wq = (const float*)d_in[2];
  const float* bq = (const float*)d_in[3];
  const float* Wk = (const float*)d_in[4];
  const float* bk = (const float*)d_in[5];
  const float* Wv = (const float*)d_in[6];
  const float* bv = (const float*)d_in[7];
  const float* Wo = (const float*)d_in[8];
  const float* bo = (const float*)d_in[9];

  char* ws = (char*)d_ws;
  u16*   Wall      = (u16*)ws;                               //   524,288 B (32 slices)
  int*   seg_start = (int*)(ws + 524288);                    //     2,052 B
  float* seg_max   = (float*)(ws + 528384);                  //    32,768 B
  float* seg_sum   = (float*)(ws + 561152);                  //    32,768 B
  float* scores    = (float*)(ws + 593920);                  // 12,800,000 B
  u16*   v_bf      = (u16*)(ws + 13393920);                  // 102,400,000 B

  float* out = (float*)d_out;
  float* att_mean = out + (size_t)NN * CC;

  const int NB = (NN + 127) / 128;   // 1563 blocks of 128 nodes

  prep_kernel<<<1024, 256, 0, stream>>>(Wq, Wk, Wv, Wo, Wall);
  seg_bounds_kernel<<<(NN + 255) / 256, 256, 0, stream>>>(batch, seg_start, NN);
  qkv_scores_kernel<<<NB, 256, 0, stream>>>(x, Wall, bq, bk, bv, v_bf, scores);
  seg_softmax_kernel<<<NG, 256, 0, stream>>>(scores, seg_start, seg_max, seg_sum);
  out_kernel<<<NB, 256, 0, stream>>>(v_bf, scores, batch, seg_max, seg_sum,
                                     Wall, bo, out, att_mean);
}

// Round 16
// 256.921 us; speedup vs baseline: 1.5040x; 1.5040x over previous
//
#include <hip/hip_runtime.h>

// Problem constants (fixed by the reference)
#define NN 200000   // nodes
#define CC 256      // channels
#define NG 512      // graphs/segments

typedef __attribute__((ext_vector_type(8))) __bf16 bf16x8;
typedef __attribute__((ext_vector_type(16))) float f32x16;

typedef unsigned short u16;

#define VWAITN(n) asm volatile("s_waitcnt vmcnt(%0)" :: "i"(n) : "memory")
#define LWAIT0()  asm volatile("s_waitcnt lgkmcnt(0)" ::: "memory")
#define SBAR() __builtin_amdgcn_s_barrier()

__device__ __forceinline__ u16 f2bf(float f) {
  union { float f; unsigned u; } v; v.f = f;
  unsigned u = v.u;
  u += 0x7fffu + ((u >> 16) & 1u);   // RNE
  return (u16)(u >> 16);
}
__device__ __forceinline__ unsigned pack2(float a, float b) {
  return (unsigned)f2bf(a) | ((unsigned)f2bf(b) << 16);
}
__device__ __forceinline__ float bflo(unsigned u){ union{unsigned u; float f;} x; x.u = u << 16; return x.f; }
__device__ __forceinline__ float bfhi(unsigned u){ union{unsigned u; float f;} x; x.u = u & 0xffff0000u; return x.f; }

// ---------------------------------------------------------------------------
// K0: prep weights into 32x32x16 MFMA A-operand fragment slices (16 KB each).
//  Slice order: 0..3 K-even, 4..7 Q-even, 8..11 K-odd, 12..15 Q-odd,
//  16..23 V, 24..31 Wo.  (unchanged — numerically proven)
// ---------------------------------------------------------------------------
__global__ __launch_bounds__(256) void prep_kernel(
    const float* __restrict__ Wq, const float* __restrict__ Wk,
    const float* __restrict__ Wv, const float* __restrict__ Wo,
    u16* __restrict__ Wall) {
  int idx = blockIdx.x * 256 + threadIdx.x;     // 0..262143
  int s = idx >> 13;
  int inner = idx & 8191;
  int ks = inner >> 9;
  int l = (inner >> 3) & 63;
  int j = inner & 7;
  int r = l & 31, hi5 = l >> 5;
  int k = ks * 16 + hi5 * 8 + j;
  const float* W; int c0;
  if (s < 16) {
    int p = s >> 3, r4 = s & 7;
    if (r4 < 4) { W = Wk; c0 = r4 * 64 + p * 32; }
    else        { W = Wq; c0 = (r4 - 4) * 64 + p * 32; }
  } else if (s < 24) { W = Wv; c0 = (s - 16) * 32; }
  else               { W = Wo; c0 = (s - 24) * 32; }
  Wall[idx] = f2bf(W[k * 256 + c0 + r]);
}

// ---------------------------------------------------------------------------
// K1: segment boundaries from sorted batch.
// ---------------------------------------------------------------------------
__global__ __launch_bounds__(256) void seg_bounds_kernel(
    const int* __restrict__ batch, int* __restrict__ seg_start, int n) {
  int i = blockIdx.x * 256 + threadIdx.x;
  if (i >= n) return;
  int a = batch[i];
  int b = (i + 1 < n) ? batch[i + 1] : NG;
  for (int g = a + 1; g <= b; ++g) seg_start[g] = i + 1;
  if (i == 0) for (int g = 0; g <= a; ++g) seg_start[g] = 0;
}

// ---------------------------------------------------------------------------
// Stage a PAIR of consecutive 16 KB W slices (32 KB) into LDS:
// 4 waves x 8 reps x 64 lanes x 16 B.  vmcnt +8 per wave per call.
// ---------------------------------------------------------------------------
__device__ __forceinline__ void stage_pair(
    const u16* __restrict__ Wall, u16* dst_base, int s0, int w, int lane) {
#pragma unroll
  for (int rep = 0; rep < 8; ++rep) {
    int unit = w * 8 + rep;            // 0..31
    const u16* src = Wall + (size_t)s0 * 8192 + (unit * 64 + lane) * 8;
    u16* dst = dst_base + unit * 512;
    __builtin_amdgcn_global_load_lds(
        (const __attribute__((address_space(1))) void*)src,
        (__attribute__((address_space(3))) void*)dst, 16, 0, 0);
  }
}

// ---------------------------------------------------------------------------
// One 32(dims)x32(nodes) slice over K=256: A-frags from LDS (16 ds_read_b128),
// B (x) from registers.  Dual accumulator chains (R7/R14-proven).
// ---------------------------------------------------------------------------
__device__ __forceinline__ f32x16 gemm_lds(
    const u16* buf, const bf16x8 xfr[16], int lane) {
  f32x16 a0 = {0.f,0.f,0.f,0.f,0.f,0.f,0.f,0.f,0.f,0.f,0.f,0.f,0.f,0.f,0.f,0.f};
  f32x16 a1 = a0;
#pragma unroll
  for (int ks = 0; ks < 16; ks += 2) {
    bf16x8 f0 = *reinterpret_cast<const bf16x8*>(&buf[(ks * 64 + lane) * 8]);
    bf16x8 f1 = *reinterpret_cast<const bf16x8*>(&buf[((ks + 1) * 64 + lane) * 8]);
    a0 = __builtin_amdgcn_mfma_f32_32x32x16_bf16(f0, xfr[ks], a0, 0, 0, 0);
    a1 = __builtin_amdgcn_mfma_f32_32x32x16_bf16(f1, xfr[ks + 1], a1, 0, 0, 0);
  }
  return a0 + a1;
}

// ---------------------------------------------------------------------------
// K2: fused QKV + scores.  4 waves x 32 nodes = 128 nodes/block.  R14 body
//  with SLICE-PAIR steps: 12 sync events instead of 24.  2 LDS pair-buffers
//  (depth-1 prefetch), counted vmcnt + raw s_barrier, biases in LDS,
//  tail index-clamped -> vmcnt-uniform blocks.
// ---------------------------------------------------------------------------
__global__ __launch_bounds__(256, 2) void qkv_scores_kernel(
    const float* __restrict__ x, const u16* __restrict__ Wall,
    const float* __restrict__ bq, const float* __restrict__ bk,
    const float* __restrict__ bv,
    u16* __restrict__ v_out,              // [NN][256] bf16
    float* __restrict__ scores) {         // [NN][16]
  __shared__ u16 Wbuf[2][16384];          // 2 x 32 KB pair buffers
  __shared__ float biasL[768];            // [bk | bq | bv]

  const int t = threadIdx.x;
  const int w = t >> 6, lane = t & 63;
  const int col = lane & 31, hi5 = lane >> 5;
  int n = blockIdx.x * 128 + w * 32 + col;
  if (n >= NN) n = NN - 1;                // clamp: duplicates write same values

  // ---- B-frags: x^T, persistent (64 VGPR). frag kb: k = kb*16+hi5*8+j ----
  bf16x8 xfr[16];
#pragma unroll
  for (int kb = 0; kb < 16; ++kb) {
    const float* px = x + (size_t)n * CC + kb * 16 + hi5 * 8;
    float4 a0 = *reinterpret_cast<const float4*>(px);
    float4 a1 = *reinterpret_cast<const float4*>(px + 4);
    uint4 u = {pack2(a0.x, a0.y), pack2(a0.z, a0.w),
               pack2(a1.x, a1.y), pack2(a1.z, a1.w)};
    xfr[kb] = *reinterpret_cast<bf16x8*>(&u);
  }
  // biases -> LDS (one-time; consumed via ds_read, off the vm counter)
  biasL[t] = bk[t];
  biasL[256 + t] = bq[t];
  biasL[512 + t] = bv[t];

  stage_pair(Wall, Wbuf[0], 0, w, lane);  // pair 0 = slices 0,1
  LWAIT0();                               // bias LDS writes done pre-barrier

  float sp[16];
#pragma unroll
  for (int i = 0; i < 16; ++i) sp[i] = 0.f;

  int bi = 0;                             // buffer holding current pair

  // ---- K/Q phases: 8 pair-steps over slices 0..15 ----
#pragma unroll 1
  for (int p = 0; p < 2; ++p) {
    unsigned kph[4][8];          // k packed bf16, head g, this half
#pragma unroll
    for (int pr = 0; pr < 2; ++pr) {      // K pairs: heads (2pr, 2pr+1)
      VWAITN(0);                 // pair stage landed (only stages in flight)
      SBAR();
      stage_pair(Wall, Wbuf[bi ^ 1], (p * 4 + pr + 1) * 2, w, lane);
#pragma unroll
      for (int sub = 0; sub < 2; ++sub) {
        const int g = pr * 2 + sub;
        f32x16 acc = gemm_lds(&Wbuf[bi][sub * 8192], xfr, lane);
#pragma unroll
        for (int q = 0; q < 4; ++q) {
          float4 b4 = *reinterpret_cast<const float4*>(
              &biasL[g * 64 + p * 32 + q * 8 + hi5 * 4]);
          kph[g][q * 2]     = pack2(acc[4 * q] + b4.x, acc[4 * q + 1] + b4.y);
          kph[g][q * 2 + 1] = pack2(acc[4 * q + 2] + b4.z, acc[4 * q + 3] + b4.w);
        }
      }
      bi ^= 1;
    }
#pragma unroll
    for (int pr = 0; pr < 2; ++pr) {      // Q pairs: heads (2pr, 2pr+1)
      VWAITN(0);
      SBAR();
      stage_pair(Wall, Wbuf[bi ^ 1], (p * 4 + 3 + pr) * 2, w, lane);
#pragma unroll
      for (int sub = 0; sub < 2; ++sub) {
        const int h = pr * 2 + sub;
        f32x16 acc = gemm_lds(&Wbuf[bi][sub * 8192], xfr, lane);
#pragma unroll
        for (int q = 0; q < 4; ++q) {
          float4 b4 = *reinterpret_cast<const float4*>(
              &biasL[256 + h * 64 + p * 32 + q * 8 + hi5 * 4]);
          float q0 = acc[4 * q] + b4.x, q1 = acc[4 * q + 1] + b4.y;
          float q2 = acc[4 * q + 2] + b4.z, q3 = acc[4 * q + 3] + b4.w;
#pragma unroll
          for (int g = 0; g < 4; ++g) {
            unsigned k01 = kph[g][q * 2];
            unsigned k23 = kph[g][q * 2 + 1];
            sp[h * 4 + g] += q0 * bflo(k01) + q1 * bfhi(k01) +
                             q2 * bflo(k23) + q3 * bfhi(k23);
          }
        }
      }
      bi ^= 1;
    }
  }

  // ---- scores reduce + store (4 store instrs, newer than V pair stage) ----
#pragma unroll
  for (int i = 0; i < 16; ++i) sp[i] += __shfl_xor(sp[i], 32, 64);
  if (hi5 == 0) {
#pragma unroll
    for (int q = 0; q < 4; ++q) {
      float4 o = {sp[q * 4] * 0.125f, sp[q * 4 + 1] * 0.125f,
                  sp[q * 4 + 2] * 0.125f, sp[q * 4 + 3] * 0.125f};
      *reinterpret_cast<float4*>(scores + (size_t)n * 16 + q * 4) = o;
    }
  }

  // ---- V phase: 4 pair-steps over slices 16..23 ----
#pragma unroll
  for (int i = 0; i < 4; ++i) {
    if (i == 0) { VWAITN(4); }   // retire stage(16,17); 4 score-stores stay
    else        { VWAITN(8); }   // retire stage; 8 v-stores stay in flight
    SBAR();
    if (i < 3) stage_pair(Wall, Wbuf[bi ^ 1], 18 + 2 * i, w, lane);
#pragma unroll
    for (int sub = 0; sub < 2; ++sub) {
      const int sv = 2 * i + sub;
      f32x16 acc = gemm_lds(&Wbuf[bi][sub * 8192], xfr, lane);
#pragma unroll
      for (int q = 0; q < 4; ++q) {
        int d0 = sv * 32 + q * 8 + hi5 * 4;
        float4 b4 = *reinterpret_cast<const float4*>(&biasL[512 + d0]);
        uint2 pk = {pack2(acc[4 * q] + b4.x, acc[4 * q + 1] + b4.y),
                    pack2(acc[4 * q + 2] + b4.z, acc[4 * q + 3] + b4.w)};
        *reinterpret_cast<uint2*>(v_out + (size_t)n * CC + d0) = pk;
      }
    }
    bi ^= 1;
  }
}

// ---------------------------------------------------------------------------
// K3: per-segment max & exp-sum over the 16 score columns (block per segment).
// ---------------------------------------------------------------------------
__global__ __launch_bounds__(256) void seg_softmax_kernel(
    const float* __restrict__ scores, const int* __restrict__ seg_start,
    float* __restrict__ seg_max, float* __restrict__ seg_sum) {
  __shared__ float red[256];
  int g = blockIdx.x;
  int s = seg_start[g], e = seg_start[g + 1];
  int t = threadIdx.x;
  int col = t & 15, sub = t >> 4;

  float m = -INFINITY;
  for (int i = s + sub; i < e; i += 16)
    m = fmaxf(m, scores[(size_t)i * 16 + col]);
  red[t] = m;
  __syncthreads();
  for (int step = 8; step >= 1; step >>= 1) {
    if (sub < step) red[t] = fmaxf(red[t], red[t + step * 16]);
    __syncthreads();
  }
  if (t < 16) seg_max[g * 16 + t] = red[t];
  float mcol = red[col];
  __syncthreads();

  float sum = 0.f;
  for (int i = s + sub; i < e; i += 16)
    sum += expf(scores[(size_t)i * 16 + col] - mcol);
  red[t] = sum;
  __syncthreads();
  for (int step = 8; step >= 1; step >>= 1) {
    if (sub < step) red[t] += red[t + step * 16];
    __syncthreads();
  }
  if (t < 16) seg_sum[g * 16 + t] = red[t];
}

// ---------------------------------------------------------------------------
// K4: fused att + att.v + output GEMM (+bo) + att_mean.  4 pair-steps over
//     Wo slices 24..31; bo in LDS; clamped tail; counted vmcnt.
// ---------------------------------------------------------------------------
__global__ __launch_bounds__(256, 2) void out_kernel(
    const u16* __restrict__ v_bf, const float* __restrict__ scores,
    const int* __restrict__ batch, const float* __restrict__ seg_max,
    const float* __restrict__ seg_sum, const u16* __restrict__ Wall,
    const float* __restrict__ bo, float* __restrict__ out,
    float* __restrict__ att_mean) {
  __shared__ u16 Wbuf[2][16384];
  __shared__ float boL[256];

  const int t = threadIdx.x;
  const int w = t >> 6, lane = t & 63;
  const int col = lane & 31, hi5 = lane >> 5;
  int n = blockIdx.x * 128 + w * 32 + col;
  if (n >= NN) n = NN - 1;                // clamp: duplicates write same values

  // ---- att[16] for this lane's node ----
  int b = batch[n];
  float att[16];
#pragma unroll
  for (int q = 0; q < 4; ++q) {
    float4 sc = *reinterpret_cast<const float4*>(scores + (size_t)n * 16 + q * 4);
    float4 mx = *reinterpret_cast<const float4*>(seg_max + b * 16 + q * 4);
    float4 sm = *reinterpret_cast<const float4*>(seg_sum + b * 16 + q * 4);
    att[q * 4 + 0] = expf(sc.x - mx.x) / (sm.x + 1e-16f);
    att[q * 4 + 1] = expf(sc.y - mx.y) / (sm.y + 1e-16f);
    att[q * 4 + 2] = expf(sc.z - mx.z) / (sm.z + 1e-16f);
    att[q * 4 + 3] = expf(sc.w - mx.w) / (sm.w + 1e-16f);
  }

  uint4 vv[4][4];   // v row, packed bf16: [g][dw]
#pragma unroll
  for (int g = 0; g < 4; ++g)
#pragma unroll
    for (int dw = 0; dw < 4; ++dw)
      vv[g][dw] = *reinterpret_cast<const uint4*>(
          v_bf + (size_t)n * CC + g * 64 + dw * 16 + hi5 * 8);

  boL[t] = bo[t];

  // att_mean store (older than stage(24,25); retired by first VWAITN(0))
  if (hi5 == 0) {
    float4 am;
    am.x = 0.25f * (att[0] + att[4] + att[8] + att[12]);
    am.y = 0.25f * (att[1] + att[5] + att[9] + att[13]);
    am.z = 0.25f * (att[2] + att[6] + att[10] + att[14]);
    am.w = 0.25f * (att[3] + att[7] + att[11] + att[15]);
    *reinterpret_cast<float4*>(att_mean + (size_t)n * 4) = am;
  }

  stage_pair(Wall, Wbuf[0], 24, w, lane);

  // ---- oa^T B-frags: oa[n][h*64+dd] = sum_g att[h*4+g]*v[n][g*64+dd] ----
  bf16x8 oaf[16];
#pragma unroll
  for (int dw = 0; dw < 4; ++dw) {
    float vr[4][8];
#pragma unroll
    for (int g = 0; g < 4; ++g) {
      uint4 u4 = vv[g][dw];
      vr[g][0] = bflo(u4.x); vr[g][1] = bfhi(u4.x);
      vr[g][2] = bflo(u4.y); vr[g][3] = bfhi(u4.y);
      vr[g][4] = bflo(u4.z); vr[g][5] = bfhi(u4.z);
      vr[g][6] = bflo(u4.w); vr[g][7] = bfhi(u4.w);
    }
#pragma unroll
    for (int h = 0; h < 4; ++h) {
      unsigned res[4];
#pragma unroll
      for (int jj = 0; jj < 4; ++jj) {
        float lo = att[h * 4 + 0] * vr[0][2 * jj] + att[h * 4 + 1] * vr[1][2 * jj] +
                   att[h * 4 + 2] * vr[2][2 * jj] + att[h * 4 + 3] * vr[3][2 * jj];
        float hf = att[h * 4 + 0] * vr[0][2 * jj + 1] + att[h * 4 + 1] * vr[1][2 * jj + 1] +
                   att[h * 4 + 2] * vr[2][2 * jj + 1] + att[h * 4 + 3] * vr[3][2 * jj + 1];
        res[jj] = pack2(lo, hf);
      }
      uint4 u = {res[0], res[1], res[2], res[3]};
      oaf[h * 4 + dw] = *reinterpret_cast<bf16x8*>(&u);
    }
  }
  LWAIT0();                               // boL visible pre-barrier

  // ---- output GEMM: 4 pair-steps over Wo slices 24..31 ----
  int bi = 0;
#pragma unroll
  for (int i = 0; i < 4; ++i) {
    if (i == 0) { VWAITN(0); }   // pair(24,25) landed (retires v/att loads too)
    else        { VWAITN(8); }   // retire pair stage; 8 out-stores in flight
    SBAR();
    if (i < 3) stage_pair(Wall, Wbuf[bi ^ 1], 26 + 2 * i, w, lane);
#pragma unroll
    for (int sub = 0; sub < 2; ++sub) {
      const int so = 2 * i + sub;
      f32x16 acc = gemm_lds(&Wbuf[bi][sub * 8192], oaf, lane);
#pragma unroll
      for (int q = 0; q < 4; ++q) {
        int c0 = so * 32 + q * 8 + hi5 * 4;
        float4 b4 = *reinterpret_cast<const float4*>(&boL[c0]);
        float4 o = {acc[4 * q] + b4.x, acc[4 * q + 1] + b4.y,
                    acc[4 * q + 2] + b4.z, acc[4 * q + 3] + b4.w};
        *reinterpret_cast<float4*>(out + (size_t)n * CC + c0) = o;
      }
    }
    bi ^= 1;
  }
}

// ---------------------------------------------------------------------------
extern "C" void kernel_launch(void* const* d_in, const int* in_sizes, int n_in,
                              void* d_out, int out_size, void* d_ws, size_t ws_size,
                              hipStream_t stream) {
  const float* x  = (const float*)d_in[0];
  const int* batch = (const int*)d_in[1];
  const float* Wq = (const float*)d_in[2];
  const float* bq = (const float*)d_in[3];
  const float* Wk = (const float*)d_in[4];
  const float* bk = (const float*)d_in[5];
  const float* Wv = (const float*)d_in[6];
  const float* bv = (const float*)d_in[7];
  const float* Wo = (const float*)d_in[8];
  const float* bo = (const float*)d_in[9];

  char* ws = (char*)d_ws;
  u16*   Wall      = (u16*)ws;                               //   524,288 B (32 slices)
  int*   seg_start = (int*)(ws + 524288);                    //     2,052 B
  float* seg_max   = (float*)(ws + 528384);                  //    32,768 B
  float* seg_sum   = (float*)(ws + 561152);                  //    32,768 B
  float* scores    = (float*)(ws + 593920);                  // 12,800,000 B
  u16*   v_bf      = (u16*)(ws + 13393920);                  // 102,400,000 B

  float* out = (float*)d_out;
  float* att_mean = out + (size_t)NN * CC;

  const int NB = (NN + 127) / 128;   // 1563 blocks of 128 nodes

  prep_kernel<<<1024, 256, 0, stream>>>(Wq, Wk, Wv, Wo, Wall);
  seg_bounds_kernel<<<(NN + 255) / 256, 256, 0, stream>>>(batch, seg_start, NN);
  qkv_scores_kernel<<<NB, 256, 0, stream>>>(x, Wall, bq, bk, bv, v_bf, scores);
  seg_softmax_kernel<<<NG, 256, 0, stream>>>(scores, seg_start, seg_max, seg_sum);
  out_kernel<<<NB, 256, 0, stream>>>(v_bf, scores, batch, seg_max, seg_sum,
                                     Wall, bo, out, att_mean);
}